// Round 7
// baseline (515.777 us; speedup 1.0000x reference)
//
#include <hip/hip_runtime.h>
#include <hip/hip_cooperative_groups.h>

namespace cg = cooperative_groups;

// Problem constants: N=50000, E=600000, D=128, G=8. All float tensors are f32.
#define D 128
#define NGRAPH 8
#define EPS 1e-5f
#define CAP 48      // neighbor bucket capacity; P(deg>48 | lambda=12)*N ~ 5e-11
#define BN 64       // nodes per fused tile
#define STATS_CHUNKS 64

typedef __attribute__((ext_vector_type(4))) float f32x4;
typedef __attribute__((ext_vector_type(8))) short s16x8;

__device__ __forceinline__ unsigned short f2bf(float f) {
    unsigned int u = __float_as_uint(f);
    u += 0x7fffu + ((u >> 16) & 1u);     // round-to-nearest-even
    return (unsigned short)(u >> 16);
}

// ===================== cooperative mega-kernel =====================
// P0: zero cnt/gsum/gsumsq, B-swizzle, x->bf16 cast, graph bounds
// P1: bucket fill (atomic)       P2: gather-mean + MFMA GEMM + GELU -> fout
// P3: per-graph sum/sumsq        P4: (sub, scale)        P5: normalize + residual
__global__ __launch_bounds__(256, 2) void mega_kernel(
    const float* __restrict__ x, const int* __restrict__ ei, const int* __restrict__ batch,
    const float* __restrict__ Wl, const float* __restrict__ bl, const float* __restrict__ Wr,
    const float* __restrict__ gw, const float* __restrict__ gb, const float* __restrict__ ms,
    float* __restrict__ out,
    float* __restrict__ fout, unsigned short* __restrict__ Bsw, unsigned int* __restrict__ xb,
    float* __restrict__ gsum, float* __restrict__ gsumsq, int* __restrict__ cnt,
    float* __restrict__ sub, float* __restrict__ scale, int* __restrict__ bnd,
    int* __restrict__ adj, int N, int E, int NBLK)
{
    cg::grid_group grid = cg::this_grid();
    __shared__ unsigned short sA[BN * 256];          // 32 KB
    const int tid  = threadIdx.x;
    const int gtid = blockIdx.x * 256 + tid;
    const int gsz  = gridDim.x * 256;
    const int wave = tid >> 6, lane = tid & 63;

    // ---------------- P0 ----------------
    for (int i = gtid; i < N; i += gsz) cnt[i] = 0;
    for (int i = gtid; i < 2 * NGRAPH * D; i += gsz) { gsum[i] = 0.0f; gsumsq[i] = 0.0f; }
    for (int t = gtid; t < 32768; t += gsz) {        // B = [Wl;Wr]^T in MFMA-fragment order
        int j    = t & 7;
        int ln   = (t >> 3) & 63;
        int ks   = (t >> 9) & 7;
        int tile = t >> 12;
        int k = ks * 32 + (ln >> 4) * 8 + j;
        int d = tile * 16 + (ln & 15);
        float v = (k < 128) ? Wl[(size_t)d * 128 + k] : Wr[(size_t)d * 128 + (k - 128)];
        Bsw[t] = f2bf(v);
    }
    for (int i = gtid; i < N * 64; i += gsz) {       // bf16 copy of x (2 feats / uint)
        float2 p = *(const float2*)(x + (size_t)i * 2);
        xb[i] = (unsigned int)f2bf(p.x) | ((unsigned int)f2bf(p.y) << 16);
    }
    if (blockIdx.x == 0 && tid <= NGRAPH) {          // graph boundaries (batch sorted)
        int g = tid, lo = 0, hi = N;
        while (lo < hi) {
            int mid = (lo + hi) >> 1;
            if (batch[mid] < g) lo = mid + 1; else hi = mid;
        }
        bnd[g] = lo;
    }
    grid.sync();

    // ---------------- P1: bucket fill ----------------
    for (int e = gtid; e < E; e += gsz) {
        int dst = ei[E + e];
        int pos = atomicAdd(&cnt[dst], 1);
        if (pos < CAP) adj[(size_t)dst * CAP + pos] = ei[e];
    }
    grid.sync();

    // ---------------- P2: gather-mean + own-x -> LDS bf16 A -> MFMA -> GELU ----------------
    for (int tb = blockIdx.x; tb < NBLK; tb += gridDim.x) {
        int n0 = tb * BN;
        // LDS row r = 512 B of 32 16-B units; unit u stored at (u ^ (r&31)) -> 2-way max
        for (int j = 0; j < 16; ++j) {
            int row  = wave * 16 + j;
            int node = n0 + row;
            float a0 = 0.0f, a1 = 0.0f;
            int deg = (node < N) ? cnt[node] : 0;
            int lim = deg < CAP ? deg : CAP;
            int v = (lane < lim) ? adj[(size_t)node * CAP + lane] : 0;
            int i = 0;
            for (; i + 4 <= lim; i += 4) {
                int nb0 = __shfl(v, i, 64),     nb1 = __shfl(v, i + 1, 64);
                int nb2 = __shfl(v, i + 2, 64), nb3 = __shfl(v, i + 3, 64);
                unsigned int u0 = xb[(size_t)nb0 * 64 + lane];
                unsigned int u1 = xb[(size_t)nb1 * 64 + lane];
                unsigned int u2 = xb[(size_t)nb2 * 64 + lane];
                unsigned int u3 = xb[(size_t)nb3 * 64 + lane];
                a0 += __uint_as_float(u0 << 16) + __uint_as_float(u1 << 16)
                    + __uint_as_float(u2 << 16) + __uint_as_float(u3 << 16);
                a1 += __uint_as_float(u0 & 0xffff0000u) + __uint_as_float(u1 & 0xffff0000u)
                    + __uint_as_float(u2 & 0xffff0000u) + __uint_as_float(u3 & 0xffff0000u);
            }
            for (; i < lim; ++i) {
                int nb = __shfl(v, i, 64);
                unsigned int u = xb[(size_t)nb * 64 + lane];
                a0 += __uint_as_float(u << 16);
                a1 += __uint_as_float(u & 0xffff0000u);
            }
            float inv = 1.0f / (float)(deg > 0 ? deg : 1);
            unsigned int pa = (unsigned int)f2bf(a0 * inv) | ((unsigned int)f2bf(a1 * inv) << 16);
            unsigned int px = (node < N) ? xb[(size_t)node * 64 + lane] : 0u;
            int ua = lane >> 2, wb = (lane & 3) << 2, rs = row & 31;
            *(unsigned int*)((char*)sA + row * 512 + (((ua)      ^ rs) << 4) + wb) = pa;
            *(unsigned int*)((char*)sA + row * 512 + (((ua + 16) ^ rs) << 4) + wb) = px;
        }
        __syncthreads();

        int m = lane & 15, quad = lane >> 4;
        int rl = wave * 16 + m, rs = rl & 31;
        s16x8 afrag[8];
#pragma unroll
        for (int ks = 0; ks < 8; ++ks) {
            int unit = ks * 4 + quad;
            afrag[ks] = *(const s16x8*)((char*)sA + rl * 512 + ((unit ^ rs) << 4));
        }
        __syncthreads();   // all afrag reads done before next iteration rewrites sA

#pragma unroll
        for (int tile = 0; tile < 8; ++tile) {
            f32x4 acc = {0.0f, 0.0f, 0.0f, 0.0f};
            const s16x8* bptr = (const s16x8*)Bsw + (size_t)(tile * 8) * 64 + lane;
#pragma unroll
            for (int ks = 0; ks < 8; ++ks)
                acc = __builtin_amdgcn_mfma_f32_16x16x32_bf16(afrag[ks], bptr[(size_t)ks * 64], acc, 0, 0, 0);
            int d = tile * 16 + m;
            float bias = bl[d];
#pragma unroll
            for (int r = 0; r < 4; ++r) {
                int node = n0 + wave * 16 + quad * 4 + r;   // C/D: col=lane&15, row=quad*4+reg
                if (node < N) {
                    float v = acc[r] + bias;
                    float g = 0.5f * v * (1.0f + erff(v * 0.70710678118654752f));
                    fout[(size_t)node * D + d] = g;
                }
            }
        }
    }
    grid.sync();

    // ---------------- P3: per-graph sum / sumsq ----------------
    {
        int per = (N + gridDim.x - 1) / gridDim.x;
        int n0 = blockIdx.x * per;
        int n1 = n0 + per; if (n1 > N) n1 = N;
        int d = tid & 127, half = tid >> 7;
        float sm = 0.0f, sq = 0.0f;
        int cur = -1;
        for (int n = n0 + half; n < n1; n += 2) {
            int g = batch[n];
            if (g != cur) {
                if (cur >= 0) {
                    unsafeAtomicAdd(&gsum[cur * D + d], sm);
                    unsafeAtomicAdd(&gsumsq[cur * D + d], sq);
                }
                cur = g; sm = 0.0f; sq = 0.0f;
            }
            float v = fout[(size_t)n * D + d];
            sm += v; sq += v * v;
        }
        if (cur >= 0) {
            unsafeAtomicAdd(&gsum[cur * D + d], sm);
            unsafeAtomicAdd(&gsumsq[cur * D + d], sq);
        }
    }
    grid.sync();

    // ---------------- P4: (sub, scale) ----------------
    if (blockIdx.x == 0) {
        for (int t = tid; t < NGRAPH * D; t += 256) {
            int g = t >> 7, d = t & (D - 1);
            int c = bnd[g + 1] - bnd[g];
            float fc = c > 0 ? (float)c : 1.0f;
            float mu = gsum[t] / fc;
            float q  = gsumsq[t] / fc;
            float a  = ms[d] * mu;
            float var = q - 2.0f * a * mu + a * a;
            sub[t] = a;
            scale[t] = rsqrtf(var + EPS);
        }
    }
    grid.sync();

    // ---------------- P5: out = (f - sub)*scale*gamma + beta + x ----------------
    for (int t = gtid; t < N * (D / 4); t += gsz) {
        int n  = t >> 5;
        int d0 = (t & 31) * 4;
        int g  = batch[n];
        size_t row = (size_t)n * D + d0;
        float4 fv = *(const float4*)(fout + row);
        float4 xv = *(const float4*)(x + row);
        float4 sb = *(const float4*)(sub + g * D + d0);
        float4 sc = *(const float4*)(scale + g * D + d0);
        float4 gwv = *(const float4*)(gw + d0);
        float4 gbv = *(const float4*)(gb + d0);
        float4 o;
        o.x = (fv.x - sb.x) * sc.x * gwv.x + gbv.x + xv.x;
        o.y = (fv.y - sb.y) * sc.y * gwv.y + gbv.y + xv.y;
        o.z = (fv.z - sb.z) * sc.z * gwv.z + gbv.z + xv.z;
        o.w = (fv.w - sb.w) * sc.w * gwv.w + gbv.w + xv.w;
        *(float4*)(out + row) = o;
    }
}

// ===================== fallback path (exact R5 structure, proven) =====================
__global__ __launch_bounds__(256) void prep_kernel(
    const float* __restrict__ Wl, const float* __restrict__ Wr,
    unsigned short* __restrict__ Bsw,
    const int* __restrict__ batch, int* __restrict__ bnd,
    const int* __restrict__ ei, int* __restrict__ cnt, int* __restrict__ adj,
    int N, int E)
{
    int b = blockIdx.x;
    if (b < 128) {
        int tid = b * 256 + threadIdx.x;
        int j    = tid & 7;
        int lane = (tid >> 3) & 63;
        int ks   = (tid >> 9) & 7;
        int tile = tid >> 12;
        int k = ks * 32 + (lane >> 4) * 8 + j;
        int d = tile * 16 + (lane & 15);
        float v = (k < 128) ? Wl[(size_t)d * 128 + k] : Wr[(size_t)d * 128 + (k - 128)];
        Bsw[tid] = f2bf(v);
    } else if (b == 128) {
        int g = threadIdx.x;
        if (g <= NGRAPH) {
            int lo = 0, hi = N;
            while (lo < hi) {
                int mid = (lo + hi) >> 1;
                if (batch[mid] < g) lo = mid + 1; else hi = mid;
            }
            bnd[g] = lo;
        }
    } else {
        int e = (b - 129) * 256 + threadIdx.x;
        if (e < E) {
            int dst = ei[E + e];
            int pos = atomicAdd(&cnt[dst], 1);
            if (pos < CAP) adj[(size_t)dst * CAP + pos] = ei[e];
        }
    }
}

__global__ __launch_bounds__(256) void fused_kernel(
    const float* __restrict__ x, const int* __restrict__ cnt,
    const int* __restrict__ adj, const unsigned short* __restrict__ Bsw,
    const float* __restrict__ bl, float* __restrict__ fout, int N)
{
    __shared__ unsigned short sA[BN * 256];
    int n0 = blockIdx.x * BN;
    int wave = threadIdx.x >> 6, lane = threadIdx.x & 63;

    for (int j = 0; j < 16; ++j) {
        int row  = wave * 16 + j;
        int node = n0 + row;
        float a0 = 0.0f, a1 = 0.0f;
        int deg = (node < N) ? cnt[node] : 0;
        int lim = deg < CAP ? deg : CAP;
        int v = (lane < lim) ? adj[(size_t)node * CAP + lane] : 0;
        int i = 0;
        for (; i + 4 <= lim; i += 4) {
            int nb0 = __shfl(v, i, 64),     nb1 = __shfl(v, i + 1, 64);
            int nb2 = __shfl(v, i + 2, 64), nb3 = __shfl(v, i + 3, 64);
            float2 p0 = *(const float2*)(x + (size_t)nb0 * D + lane * 2);
            float2 p1 = *(const float2*)(x + (size_t)nb1 * D + lane * 2);
            float2 p2 = *(const float2*)(x + (size_t)nb2 * D + lane * 2);
            float2 p3 = *(const float2*)(x + (size_t)nb3 * D + lane * 2);
            a0 += p0.x + p1.x + p2.x + p3.x;
            a1 += p0.y + p1.y + p2.y + p3.y;
        }
        for (; i < lim; ++i) {
            int nb = __shfl(v, i, 64);
            float2 p = *(const float2*)(x + (size_t)nb * D + lane * 2);
            a0 += p.x; a1 += p.y;
        }
        float inv = 1.0f / (float)(deg > 0 ? deg : 1);
        float2 xo = make_float2(0.0f, 0.0f);
        if (node < N) xo = *(const float2*)(x + (size_t)node * D + lane * 2);
        unsigned int pa = (unsigned int)f2bf(a0 * inv) | ((unsigned int)f2bf(a1 * inv) << 16);
        unsigned int px = (unsigned int)f2bf(xo.x) | ((unsigned int)f2bf(xo.y) << 16);
        int ua = lane >> 2, wb = (lane & 3) << 2, rs = row & 31;
        *(unsigned int*)((char*)sA + row * 512 + (((ua)      ^ rs) << 4) + wb) = pa;
        *(unsigned int*)((char*)sA + row * 512 + (((ua + 16) ^ rs) << 4) + wb) = px;
    }
    __syncthreads();

    int m = lane & 15, quad = lane >> 4;
    int rl = wave * 16 + m, rs = rl & 31;
    s16x8 afrag[8];
#pragma unroll
    for (int ks = 0; ks < 8; ++ks) {
        int unit = ks * 4 + quad;
        afrag[ks] = *(const s16x8*)((char*)sA + rl * 512 + ((unit ^ rs) << 4));
    }
#pragma unroll
    for (int tile = 0; tile < 8; ++tile) {
        f32x4 acc = {0.0f, 0.0f, 0.0f, 0.0f};
        const s16x8* bptr = (const s16x8*)Bsw + (size_t)(tile * 8) * 64 + lane;
#pragma unroll
        for (int ks = 0; ks < 8; ++ks)
            acc = __builtin_amdgcn_mfma_f32_16x16x32_bf16(afrag[ks], bptr[(size_t)ks * 64], acc, 0, 0, 0);
        int d = tile * 16 + m;
        float bias = bl[d];
#pragma unroll
        for (int r = 0; r < 4; ++r) {
            int node = n0 + wave * 16 + quad * 4 + r;
            if (node < N) {
                float v = acc[r] + bias;
                float g = 0.5f * v * (1.0f + erff(v * 0.70710678118654752f));
                fout[(size_t)node * D + d] = g;
            }
        }
    }
}

__global__ __launch_bounds__(128) void stats_kernel(
    const float* __restrict__ f, const int* __restrict__ bnd,
    float* __restrict__ gsum, float* __restrict__ gsumsq)
{
    int g = blockIdx.x / STATS_CHUNKS;
    int c = blockIdx.x % STATS_CHUNKS;
    int s = bnd[g], e = bnd[g + 1];
    int cnt = e - s;
    int chunk = (cnt + STATS_CHUNKS - 1) / STATS_CHUNKS;
    int n0 = s + c * chunk;
    int n1 = n0 + chunk; if (n1 > e) n1 = e;
    if (n0 >= n1) return;
    int d = threadIdx.x;
    float sm = 0.0f, sq = 0.0f;
    for (int n = n0; n < n1; ++n) {
        float v = f[(size_t)n * D + d];
        sm += v;
        sq += v * v;
    }
    unsafeAtomicAdd(&gsum[g * D + d], sm);
    unsafeAtomicAdd(&gsumsq[g * D + d], sq);
}

__global__ void finalize_kernel(
    const float* __restrict__ gsum, const float* __restrict__ gsumsq,
    const int* __restrict__ bnd, const float* __restrict__ ms,
    float* __restrict__ sub, float* __restrict__ scale)
{
    int t = blockIdx.x * blockDim.x + threadIdx.x;
    if (t >= NGRAPH * D) return;
    int g = t >> 7, d = t & (D - 1);
    int cnt = bnd[g + 1] - bnd[g];
    float fc = cnt > 0 ? (float)cnt : 1.0f;
    float mu = gsum[t] / fc;
    float q  = gsumsq[t] / fc;
    float a  = ms[d] * mu;
    float var = q - 2.0f * a * mu + a * a;
    sub[t] = a;
    scale[t] = rsqrtf(var + EPS);
}

__global__ __launch_bounds__(256) void final_kernel(
    const float* __restrict__ f, const float* __restrict__ x,
    const int* __restrict__ batch,
    const float* __restrict__ sub, const float* __restrict__ scale,
    const float* __restrict__ gw, const float* __restrict__ gb,
    float* __restrict__ out, int N)
{
    int t = blockIdx.x * 256 + threadIdx.x;
    if (t >= N * (D / 4)) return;
    int n  = t >> 5;
    int d0 = (t & 31) * 4;
    int g  = batch[n];
    size_t row = (size_t)n * D + d0;
    float4 fv = *(const float4*)(f + row);
    float4 xv = *(const float4*)(x + row);
    float4 sb = *(const float4*)(sub + g * D + d0);
    float4 sc = *(const float4*)(scale + g * D + d0);
    float4 gwv = *(const float4*)(gw + d0);
    float4 gbv = *(const float4*)(gb + d0);
    float4 o;
    o.x = (fv.x - sb.x) * sc.x * gwv.x + gbv.x + xv.x;
    o.y = (fv.y - sb.y) * sc.y * gwv.y + gbv.y + xv.y;
    o.z = (fv.z - sb.z) * sc.z * gwv.z + gbv.z + xv.z;
    o.w = (fv.w - sb.w) * sc.w * gwv.w + gbv.w + xv.w;
    *(float4*)(out + row) = o;
}

extern "C" void kernel_launch(void* const* d_in, const int* in_sizes, int n_in,
                              void* d_out, int out_size, void* d_ws, size_t ws_size,
                              hipStream_t stream)
{
    const float* x     = (const float*)d_in[0];
    const int*   ei    = (const int*)d_in[1];
    const int*   batch = (const int*)d_in[2];
    const float* Wl = (const float*)d_in[4];
    const float* bl = (const float*)d_in[5];
    const float* Wr = (const float*)d_in[6];
    const float* gw = (const float*)d_in[7];
    const float* gb = (const float*)d_in[8];
    const float* ms = (const float*)d_in[9];
    float* out = (float*)d_out;

    int N = in_sizes[0] / D;
    int E = in_sizes[1] / 2;
    int NBLK = (N + BN - 1) / BN;                // 782 tiles
    const int Npad = NBLK * BN;

    // workspace layout:
    //   fout [Npad*128 f32] | xb [N*64 uint] | Bsw [32768 bf16]
    //   gsum | gsumsq | sub | scale [G*D f32 each]
    //   cnt[N] int | bnd[G+1] int | adj[N*CAP] int
    float*          fout = (float*)d_ws;
    unsigned int*   xb   = (unsigned int*)(fout + (size_t)Npad * D);
    unsigned short* Bsw  = (unsigned short*)(xb + (size_t)N * 64);
    float* gsum   = (float*)(Bsw + 32768);
    float* gsumsq = gsum + NGRAPH * D;
    float* sub    = gsumsq + NGRAPH * D;
    float* scale  = sub + NGRAPH * D;
    int*   cnt    = (int*)(scale + NGRAPH * D);
    int*   bnd    = cnt + N;
    int*   adj    = bnd + (NGRAPH + 1);

    // Decide launch mode (host-side queries only; deterministic per device).
    int dev = 0;
    hipGetDevice(&dev);
    int coop = 0;
    hipDeviceGetAttribute(&coop, hipDeviceAttributeCooperativeLaunch, dev);
    int cus = 0;
    hipDeviceGetAttribute(&cus, hipDeviceAttributeMultiprocessorCount, dev);
    int maxB = 0;
    hipError_t occ_st = hipOccupancyMaxActiveBlocksPerMultiprocessor(
        &maxB, (const void*)mega_kernel, 256, 0);

    if (coop && occ_st == hipSuccess && maxB > 0 && cus > 0) {
        int grid = maxB * cus;                   // co-resident by construction
        void* args[] = {
            (void*)&x, (void*)&ei, (void*)&batch, (void*)&Wl, (void*)&bl, (void*)&Wr,
            (void*)&gw, (void*)&gb, (void*)&ms, (void*)&out,
            (void*)&fout, (void*)&Bsw, (void*)&xb, (void*)&gsum, (void*)&gsumsq,
            (void*)&cnt, (void*)&sub, (void*)&scale, (void*)&bnd, (void*)&adj,
            (void*)&N, (void*)&E, (void*)&NBLK
        };
        hipLaunchCooperativeKernel((const void*)mega_kernel, dim3(grid), dim3(256),
                                   args, 0, stream);
    } else {
        // Fallback: proven R5 multi-kernel path (f32 gather, no xb).
        hipMemsetAsync(gsum, 0, (2 * NGRAPH * D) * sizeof(float), stream);
        hipMemsetAsync(cnt, 0, (size_t)N * sizeof(int), stream);
        int fill_blocks = (E + 255) / 256;
        prep_kernel<<<129 + fill_blocks, 256, 0, stream>>>(
            Wl, Wr, Bsw, batch, bnd, ei, cnt, adj, N, E);
        fused_kernel<<<NBLK, 256, 0, stream>>>(x, cnt, adj, Bsw, bl, fout, N);
        stats_kernel<<<NGRAPH * STATS_CHUNKS, 128, 0, stream>>>(fout, bnd, gsum, gsumsq);
        finalize_kernel<<<(NGRAPH * D + 255) / 256, 256, 0, stream>>>(gsum, gsumsq, bnd, ms, sub, scale);
        int threads = N * (D / 4);
        final_kernel<<<(threads + 255) / 256, 256, 0, stream>>>(
            fout, x, batch, sub, scale, gw, gb, out, N);
    }
}

// Round 8
// 214.997 us; speedup vs baseline: 2.3990x; 2.3990x over previous
//
#include <hip/hip_runtime.h>
#include <hip/hip_bf16.h>

// Problem constants: N=50000, E=600000, D=128, G=8. All float tensors are f32.
#define D 128
#define NGRAPH 8
#define EPS 1e-5f
#define CAP 48      // neighbor bucket capacity; P(deg>48 | lambda=12)*N ~ 5e-11
#define BN 64       // nodes per fused tile

typedef __attribute__((ext_vector_type(4))) float f32x4;
typedef __attribute__((ext_vector_type(8))) short s16x8;

__device__ __forceinline__ unsigned short f2bf(float f) {
    unsigned int u = __float_as_uint(f);
    u += 0x7fffu + ((u >> 16) & 1u);     // round-to-nearest-even
    return (unsigned short)(u >> 16);
}

// ---- D1 prep: zero cnt/gsum/gsumsq + B-swizzle + x->bf16 cast + graph bounds ----
__global__ __launch_bounds__(256) void prep_kernel(
    const float* __restrict__ Wl, const float* __restrict__ Wr,
    unsigned short* __restrict__ Bsw,
    const float* __restrict__ x, unsigned int* __restrict__ xb,
    const int* __restrict__ batch, int* __restrict__ bnd,
    int* __restrict__ cnt, float* __restrict__ gsum, float* __restrict__ gsumsq,
    int N)
{
    int gtid = blockIdx.x * 256 + threadIdx.x;
    int gsz  = gridDim.x * 256;
    for (int i = gtid; i < N; i += gsz) cnt[i] = 0;
    for (int i = gtid; i < 2 * NGRAPH * D; i += gsz) { gsum[i] = 0.0f; gsumsq[i] = 0.0f; }
    for (int t = gtid; t < 32768; t += gsz) {        // B = [Wl;Wr]^T in MFMA-fragment order
        int j    = t & 7;
        int ln   = (t >> 3) & 63;
        int ks   = (t >> 9) & 7;
        int tile = t >> 12;
        int k = ks * 32 + (ln >> 4) * 8 + j;
        int d = tile * 16 + (ln & 15);
        float v = (k < 128) ? Wl[(size_t)d * 128 + k] : Wr[(size_t)d * 128 + (k - 128)];
        Bsw[t] = f2bf(v);
    }
    for (int i = gtid; i < N * 64; i += gsz) {       // bf16 copy of x (2 feats / uint)
        float2 p = *(const float2*)(x + (size_t)i * 2);
        xb[i] = (unsigned int)f2bf(p.x) | ((unsigned int)f2bf(p.y) << 16);
    }
    if (gtid <= NGRAPH) {                            // graph boundaries (batch sorted)
        int g = gtid, lo = 0, hi = N;
        while (lo < hi) {
            int mid = (lo + hi) >> 1;
            if (batch[mid] < g) lo = mid + 1; else hi = mid;
        }
        bnd[g] = lo;
    }
}

// ---- D2: bucket fill (cnt zeroed by D1) ----
__global__ __launch_bounds__(256) void fill_kernel(
    const int* __restrict__ ei, int* __restrict__ cursor,
    int* __restrict__ adj, int E)
{
    int e = blockIdx.x * 256 + threadIdx.x;
    if (e < E) {
        int dst = ei[E + e];
        int pos = atomicAdd(&cursor[dst], 1);
        if (pos < CAP) adj[(size_t)dst * CAP + pos] = ei[e];
    }
}

// ---- D3 fused: bf16 gather-mean -> LDS A -> MFMA -> GELU -> fout + per-graph stats ----
// Block = 256 thr (4 waves) = 64 nodes; wave w handles nodes [n0+16w, n0+16w+16).
__global__ __launch_bounds__(256) void fused_kernel(
    const unsigned int* __restrict__ xb, const int* __restrict__ cnt,
    const int* __restrict__ adj, const unsigned short* __restrict__ Bsw,
    const float* __restrict__ bl, const int* __restrict__ batch,
    float* __restrict__ fout, float* __restrict__ gsum, float* __restrict__ gsumsq,
    int N)
{
    __shared__ unsigned short sA[BN * 256];          // 32 KB
    int n0 = blockIdx.x * BN;
    int wave = threadIdx.x >> 6, lane = threadIdx.x & 63;

    // phase 1: gather-mean (bf16 reads, f32 accum) + own x -> LDS, XOR-swizzled
    for (int j = 0; j < 16; ++j) {
        int row  = wave * 16 + j;
        int node = n0 + row;
        float a0 = 0.0f, a1 = 0.0f;
        int deg = (node < N) ? cnt[node] : 0;
        int lim = deg < CAP ? deg : CAP;
        int v = (lane < lim) ? adj[(size_t)node * CAP + lane] : 0;
        int i = 0;
        for (; i + 4 <= lim; i += 4) {
            int nb0 = __shfl(v, i, 64),     nb1 = __shfl(v, i + 1, 64);
            int nb2 = __shfl(v, i + 2, 64), nb3 = __shfl(v, i + 3, 64);
            unsigned int u0 = xb[(size_t)nb0 * 64 + lane];
            unsigned int u1 = xb[(size_t)nb1 * 64 + lane];
            unsigned int u2 = xb[(size_t)nb2 * 64 + lane];
            unsigned int u3 = xb[(size_t)nb3 * 64 + lane];
            a0 += __uint_as_float(u0 << 16) + __uint_as_float(u1 << 16)
                + __uint_as_float(u2 << 16) + __uint_as_float(u3 << 16);
            a1 += __uint_as_float(u0 & 0xffff0000u) + __uint_as_float(u1 & 0xffff0000u)
                + __uint_as_float(u2 & 0xffff0000u) + __uint_as_float(u3 & 0xffff0000u);
        }
        for (; i < lim; ++i) {
            int nb = __shfl(v, i, 64);
            unsigned int u = xb[(size_t)nb * 64 + lane];
            a0 += __uint_as_float(u << 16);
            a1 += __uint_as_float(u & 0xffff0000u);
        }
        float inv = 1.0f / (float)(deg > 0 ? deg : 1);
        unsigned int pa = (unsigned int)f2bf(a0 * inv) | ((unsigned int)f2bf(a1 * inv) << 16);
        unsigned int px = (node < N) ? xb[(size_t)node * 64 + lane] : 0u;
        int ua = lane >> 2, wb = (lane & 3) << 2, rs = row & 31;
        *(unsigned int*)((char*)sA + row * 512 + (((ua)      ^ rs) << 4) + wb) = pa;
        *(unsigned int*)((char*)sA + row * 512 + (((ua + 16) ^ rs) << 4) + wb) = px;
    }
    __syncthreads();

    // phase 2: MFMA + GELU epilogue + fused per-graph stats
    int m = lane & 15, quad = lane >> 4;
    int rl = wave * 16 + m, rs = rl & 31;
    s16x8 afrag[8];
#pragma unroll
    for (int ks = 0; ks < 8; ++ks) {
        int unit = ks * 4 + quad;
        afrag[ks] = *(const s16x8*)((char*)sA + rl * 512 + ((unit ^ rs) << 4));
    }

    int nbase = n0 + wave * 16;
    bool uni = (nbase + 15 < N) && (batch[nbase] == batch[nbase + 15]);
    int gu = (nbase < N) ? batch[nbase] : 0;

#pragma unroll
    for (int tile = 0; tile < 8; ++tile) {
        f32x4 acc = {0.0f, 0.0f, 0.0f, 0.0f};
        const s16x8* bptr = (const s16x8*)Bsw + (size_t)(tile * 8) * 64 + lane;
#pragma unroll
        for (int ks = 0; ks < 8; ++ks)
            acc = __builtin_amdgcn_mfma_f32_16x16x32_bf16(afrag[ks], bptr[(size_t)ks * 64], acc, 0, 0, 0);
        int d = tile * 16 + m;
        float bias = bl[d];
        float sm = 0.0f, sq = 0.0f;
#pragma unroll
        for (int r = 0; r < 4; ++r) {
            int node = nbase + quad * 4 + r;    // C/D: col=lane&15, row=quad*4+reg
            if (node < N) {
                float v = acc[r] + bias;
                float g = 0.5f * v * (1.0f + erff(v * 0.70710678118654752f));
                fout[(size_t)node * D + d] = g;
                if (uni) { sm += g; sq += g * g; }
                else {
                    int gg = batch[node];
                    unsafeAtomicAdd(&gsum[gg * D + d], g);
                    unsafeAtomicAdd(&gsumsq[gg * D + d], g * g);
                }
            }
        }
        if (uni) {
            // reduce over the 4 quads (lanes differing in bits 4,5) -> lane quad 0 holds tile sum
            sm += __shfl_xor(sm, 16, 64); sm += __shfl_xor(sm, 32, 64);
            sq += __shfl_xor(sq, 16, 64); sq += __shfl_xor(sq, 32, 64);
            if (quad == 0) {
                unsafeAtomicAdd(&gsum[gu * D + d], sm);
                unsafeAtomicAdd(&gsumsq[gu * D + d], sq);
            }
        }
    }
}

// ---- D4 final: inline (sub,scale) from gsum/gsumsq; out = (f-sub)*scale*gw + gb + x ----
__global__ __launch_bounds__(256) void final_kernel(
    const float* __restrict__ f, const float* __restrict__ x,
    const int* __restrict__ batch, const int* __restrict__ bnd,
    const float* __restrict__ gsum, const float* __restrict__ gsumsq,
    const float* __restrict__ ms,
    const float* __restrict__ gw, const float* __restrict__ gb,
    float* __restrict__ out, int N)
{
    int t = blockIdx.x * 256 + threadIdx.x;      // one thread per 4 features
    if (t >= N * (D / 4)) return;
    int n  = t >> 5;
    int d0 = (t & 31) * 4;
    int g  = batch[n];
    int c  = bnd[g + 1] - bnd[g];
    float invc = 1.0f / (float)(c > 0 ? c : 1);
    size_t row = (size_t)n * D + d0;
    float4 fv = *(const float4*)(f + row);
    float4 xv = *(const float4*)(x + row);
    float4 s1 = *(const float4*)(gsum + g * D + d0);
    float4 s2 = *(const float4*)(gsumsq + g * D + d0);
    float4 msv = *(const float4*)(ms + d0);
    float4 gwv = *(const float4*)(gw + d0);
    float4 gbv = *(const float4*)(gb + d0);
    float4 o;
    {
        float mu = s1.x * invc, q = s2.x * invc, a = msv.x * mu;
        float sc = rsqrtf(q - 2.0f * a * mu + a * a + EPS);
        o.x = (fv.x - a) * sc * gwv.x + gbv.x + xv.x;
    }
    {
        float mu = s1.y * invc, q = s2.y * invc, a = msv.y * mu;
        float sc = rsqrtf(q - 2.0f * a * mu + a * a + EPS);
        o.y = (fv.y - a) * sc * gwv.y + gbv.y + xv.y;
    }
    {
        float mu = s1.z * invc, q = s2.z * invc, a = msv.z * mu;
        float sc = rsqrtf(q - 2.0f * a * mu + a * a + EPS);
        o.z = (fv.z - a) * sc * gwv.z + gbv.z + xv.z;
    }
    {
        float mu = s1.w * invc, q = s2.w * invc, a = msv.w * mu;
        float sc = rsqrtf(q - 2.0f * a * mu + a * a + EPS);
        o.w = (fv.w - a) * sc * gwv.w + gbv.w + xv.w;
    }
    *(float4*)(out + row) = o;
}

extern "C" void kernel_launch(void* const* d_in, const int* in_sizes, int n_in,
                              void* d_out, int out_size, void* d_ws, size_t ws_size,
                              hipStream_t stream)
{
    const float* x     = (const float*)d_in[0];
    const int*   ei    = (const int*)d_in[1];
    const int*   batch = (const int*)d_in[2];
    const float* Wl = (const float*)d_in[4];
    const float* bl = (const float*)d_in[5];
    const float* Wr = (const float*)d_in[6];
    const float* gw = (const float*)d_in[7];
    const float* gb = (const float*)d_in[8];
    const float* ms = (const float*)d_in[9];
    float* out = (float*)d_out;

    int N = in_sizes[0] / D;
    int E = in_sizes[1] / 2;
    int NBLK = (N + BN - 1) / BN;                // 782 tiles
    const int Npad = NBLK * BN;

    // workspace layout:
    //   fout [Npad*128 f32] | xb [N*64 uint] | Bsw [32768 bf16]
    //   gsum | gsumsq [G*D f32 each]
    //   cnt[N] int | bnd[G+1] int | adj[N*CAP] int
    float*          fout = (float*)d_ws;
    unsigned int*   xb   = (unsigned int*)(fout + (size_t)Npad * D);
    unsigned short* Bsw  = (unsigned short*)(xb + (size_t)N * 64);
    float* gsum   = (float*)(Bsw + 32768);
    float* gsumsq = gsum + NGRAPH * D;
    int*   cnt    = (int*)(gsumsq + NGRAPH * D);
    int*   bnd    = cnt + N;
    int*   adj    = bnd + (NGRAPH + 1);

    prep_kernel<<<512, 256, 0, stream>>>(Wl, Wr, Bsw, x, xb, batch, bnd,
                                         cnt, gsum, gsumsq, N);

    fill_kernel<<<(E + 255) / 256, 256, 0, stream>>>(ei, cnt, adj, E);

    fused_kernel<<<NBLK, 256, 0, stream>>>(xb, cnt, adj, Bsw, bl, batch,
                                           fout, gsum, gsumsq, N);

    {
        int threads = N * (D / 4);
        final_kernel<<<(threads + 255) / 256, 256, 0, stream>>>(
            fout, x, batch, bnd, gsum, gsumsq, ms, gw, gb, out, N);
    }
}

// Round 9
// 198.922 us; speedup vs baseline: 2.5929x; 1.0808x over previous
//
#include <hip/hip_runtime.h>
#include <hip/hip_bf16.h>

// Problem constants: N=50000, E=600000, D=128, G=8. All float tensors are f32.
#define D 128
#define NGRAPH 8
#define EPS 1e-5f
#define CAP 48      // neighbor bucket capacity; P(deg>48 | lambda=12)*N ~ 5e-11

typedef __attribute__((ext_vector_type(4))) float f32x4;
typedef __attribute__((ext_vector_type(8))) short s16x8;

__device__ __forceinline__ unsigned short f2bf(float f) {
    unsigned int u = __float_as_uint(f);
    u += 0x7fffu + ((u >> 16) & 1u);     // round-to-nearest-even
    return (unsigned short)(u >> 16);
}
__device__ __forceinline__ float blo(unsigned int u) { return __uint_as_float(u << 16); }
__device__ __forceinline__ float bhi(unsigned int u) { return __uint_as_float(u & 0xffff0000u); }

// ---- D2 prep_fill (block-ranged): [0,128) Bsw | [128] bounds | fill edges | xb cast ----
__global__ __launch_bounds__(256) void prep_fill_kernel(
    const float* __restrict__ Wl, const float* __restrict__ Wr,
    unsigned short* __restrict__ Bsw,
    const float* __restrict__ x, unsigned int* __restrict__ xb,
    const int* __restrict__ batch, int* __restrict__ bnd,
    const int* __restrict__ ei, int* __restrict__ cnt, int* __restrict__ adj,
    int N, int E, int Npad, int fillB)
{
    int b = blockIdx.x;
    if (b < 128) {                      // B = [Wl;Wr]^T in MFMA-fragment order
        int t = b * 256 + threadIdx.x;             // 0..32767
        int j    = t & 7;
        int ln   = (t >> 3) & 63;
        int ks   = (t >> 9) & 7;
        int tile = t >> 12;
        int k = ks * 32 + (ln >> 4) * 8 + j;
        int d = tile * 16 + (ln & 15);
        float v = (k < 128) ? Wl[(size_t)d * 128 + k] : Wr[(size_t)d * 128 + (k - 128)];
        Bsw[t] = f2bf(v);
    } else if (b == 128) {              // graph boundaries (batch sorted)
        int g = threadIdx.x;
        if (g <= NGRAPH) {
            int lo = 0, hi = N;
            while (lo < hi) {
                int mid = (lo + hi) >> 1;
                if (batch[mid] < g) lo = mid + 1; else hi = mid;
            }
            bnd[g] = lo;
        }
    } else if (b < 129 + fillB) {       // bucket fill (cnt zeroed by memset)
        int e = (b - 129) * 256 + threadIdx.x;
        if (e < E) {
            int dst = ei[E + e];
            int pos = atomicAdd(&cnt[dst], 1);
            if (pos < CAP) adj[(size_t)dst * CAP + pos] = ei[e];
        }
    } else {                            // x -> bf16 (2 feats/uint), zero-padded to Npad rows
        int iu = (b - 129 - fillB) * 256 + threadIdx.x;   // uint2 index
        if (iu < N * 32) {
            float4 p = *(const float4*)(x + (size_t)iu * 4);
            uint2 o;
            o.x = (unsigned int)f2bf(p.x) | ((unsigned int)f2bf(p.y) << 16);
            o.y = (unsigned int)f2bf(p.z) | ((unsigned int)f2bf(p.w) << 16);
            *(uint2*)(xb + (size_t)iu * 2) = o;
        } else if (iu < Npad * 32) {
            *(uint2*)(xb + (size_t)iu * 2) = make_uint2(0u, 0u);
        }
    }
}

// ---- D3 aggregate: 1 wave/node, no LDS, unroll-8 bf16 gather -> Aag (bf16, k=0..127) ----
__global__ __launch_bounds__(256) void aggregate_kernel(
    const unsigned int* __restrict__ xb, const int* __restrict__ cnt,
    const int* __restrict__ adj, unsigned int* __restrict__ Aag, int N, int Npad)
{
    int n = blockIdx.x * 4 + (threadIdx.x >> 6);
    int lane = threadIdx.x & 63;
    if (n >= Npad) return;
    if (n >= N) { Aag[(size_t)n * 64 + lane] = 0u; return; }
    int deg = cnt[n];
    int lim = deg < CAP ? deg : CAP;
    int v = (lane < lim) ? adj[(size_t)n * CAP + lane] : 0;
    float a0 = 0.0f, a1 = 0.0f;
    int i = 0;
    for (; i + 8 <= lim; i += 8) {
        int nb[8];
#pragma unroll
        for (int k = 0; k < 8; ++k) nb[k] = __shfl(v, i + k, 64);
        unsigned int u[8];
#pragma unroll
        for (int k = 0; k < 8; ++k) u[k] = xb[(size_t)nb[k] * 64 + lane];
#pragma unroll
        for (int k = 0; k < 8; ++k) { a0 += blo(u[k]); a1 += bhi(u[k]); }
    }
    for (; i < lim; ++i) {
        int nb = __shfl(v, i, 64);
        unsigned int u = xb[(size_t)nb * 64 + lane];
        a0 += blo(u); a1 += bhi(u);
    }
    float inv = 1.0f / (float)(deg > 0 ? deg : 1);
    Aag[(size_t)n * 64 + lane] =
        (unsigned int)f2bf(a0 * inv) | ((unsigned int)f2bf(a1 * inv) << 16);
}

// ---- D4 gemm: LDS-free; A-fragments direct from global (Aag k<128, xb k>=128) ----
// 1 wave per 16 nodes; 8 tiles x 8 ksteps mfma_f32_16x16x32_bf16; GELU + fused stats.
__global__ __launch_bounds__(256) void gemm_kernel(
    const unsigned short* __restrict__ Aag, const unsigned short* __restrict__ xb16,
    const unsigned short* __restrict__ Bsw, const float* __restrict__ bl,
    const int* __restrict__ batch,
    float* __restrict__ fout, float* __restrict__ gsum, float* __restrict__ gsumsq,
    int N)
{
    int wave = threadIdx.x >> 6, lane = threadIdx.x & 63;
    int row0 = blockIdx.x * 64 + wave * 16;
    int m = lane & 15, quad = lane >> 4;
    int r = row0 + m;

    s16x8 afrag[8];
    const unsigned short* ab = Aag + (size_t)r * 128 + quad * 8;
#pragma unroll
    for (int ks = 0; ks < 4; ++ks) afrag[ks] = *(const s16x8*)(ab + ks * 32);
    const unsigned short* xp = xb16 + (size_t)r * 128 + quad * 8;
#pragma unroll
    for (int ks = 0; ks < 4; ++ks) afrag[4 + ks] = *(const s16x8*)(xp + ks * 32);

    int nbase = row0;
    bool uni = (nbase + 15 < N) && (batch[nbase] == batch[nbase + 15]);
    int gu = (nbase < N) ? batch[nbase] : 0;

#pragma unroll
    for (int tile = 0; tile < 8; ++tile) {
        f32x4 acc = {0.0f, 0.0f, 0.0f, 0.0f};
        const s16x8* bptr = (const s16x8*)Bsw + (size_t)(tile * 8) * 64 + lane;
#pragma unroll
        for (int ks = 0; ks < 8; ++ks)
            acc = __builtin_amdgcn_mfma_f32_16x16x32_bf16(afrag[ks], bptr[(size_t)ks * 64], acc, 0, 0, 0);
        int d = tile * 16 + m;
        float bias = bl[d];
        float sm = 0.0f, sq = 0.0f;
#pragma unroll
        for (int rr = 0; rr < 4; ++rr) {
            int node = nbase + quad * 4 + rr;   // C/D: col=lane&15, row=quad*4+reg
            if (node < N) {
                float v = acc[rr] + bias;
                float g = 0.5f * v * (1.0f + erff(v * 0.70710678118654752f));
                fout[(size_t)node * D + d] = g;
                if (uni) { sm += g; sq += g * g; }
                else {
                    int gg = batch[node];
                    unsafeAtomicAdd(&gsum[gg * D + d], g);
                    unsafeAtomicAdd(&gsumsq[gg * D + d], g * g);
                }
            }
        }
        if (uni) {
            sm += __shfl_xor(sm, 16, 64); sm += __shfl_xor(sm, 32, 64);
            sq += __shfl_xor(sq, 16, 64); sq += __shfl_xor(sq, 32, 64);
            if (quad == 0) {
                unsafeAtomicAdd(&gsum[gu * D + d], sm);
                unsafeAtomicAdd(&gsumsq[gu * D + d], sq);
            }
        }
    }
}

// ---- D5 final: inline (sub,scale); out = (f-sub)*scale*gw + gb + x ----
__global__ __launch_bounds__(256) void final_kernel(
    const float* __restrict__ f, const float* __restrict__ x,
    const int* __restrict__ batch, const int* __restrict__ bnd,
    const float* __restrict__ gsum, const float* __restrict__ gsumsq,
    const float* __restrict__ ms,
    const float* __restrict__ gw, const float* __restrict__ gb,
    float* __restrict__ out, int N)
{
    int t = blockIdx.x * 256 + threadIdx.x;      // one thread per 4 features
    if (t >= N * (D / 4)) return;
    int n  = t >> 5;
    int d0 = (t & 31) * 4;
    int g  = batch[n];
    int c  = bnd[g + 1] - bnd[g];
    float invc = 1.0f / (float)(c > 0 ? c : 1);
    size_t row = (size_t)n * D + d0;
    float4 fv = *(const float4*)(f + row);
    float4 xv = *(const float4*)(x + row);
    float4 s1 = *(const float4*)(gsum + g * D + d0);
    float4 s2 = *(const float4*)(gsumsq + g * D + d0);
    float4 msv = *(const float4*)(ms + d0);
    float4 gwv = *(const float4*)(gw + d0);
    float4 gbv = *(const float4*)(gb + d0);
    float4 o;
    {
        float mu = s1.x * invc, q = s2.x * invc, a = msv.x * mu;
        float sc = rsqrtf(q - 2.0f * a * mu + a * a + EPS);
        o.x = (fv.x - a) * sc * gwv.x + gbv.x + xv.x;
    }
    {
        float mu = s1.y * invc, q = s2.y * invc, a = msv.y * mu;
        float sc = rsqrtf(q - 2.0f * a * mu + a * a + EPS);
        o.y = (fv.y - a) * sc * gwv.y + gbv.y + xv.y;
    }
    {
        float mu = s1.z * invc, q = s2.z * invc, a = msv.z * mu;
        float sc = rsqrtf(q - 2.0f * a * mu + a * a + EPS);
        o.z = (fv.z - a) * sc * gwv.z + gbv.z + xv.z;
    }
    {
        float mu = s1.w * invc, q = s2.w * invc, a = msv.w * mu;
        float sc = rsqrtf(q - 2.0f * a * mu + a * a + EPS);
        o.w = (fv.w - a) * sc * gwv.w + gbv.w + xv.w;
    }
    *(float4*)(out + row) = o;
}

extern "C" void kernel_launch(void* const* d_in, const int* in_sizes, int n_in,
                              void* d_out, int out_size, void* d_ws, size_t ws_size,
                              hipStream_t stream)
{
    const float* x     = (const float*)d_in[0];
    const int*   ei    = (const int*)d_in[1];
    const int*   batch = (const int*)d_in[2];
    const float* Wl = (const float*)d_in[4];
    const float* bl = (const float*)d_in[5];
    const float* Wr = (const float*)d_in[6];
    const float* gw = (const float*)d_in[7];
    const float* gb = (const float*)d_in[8];
    const float* ms = (const float*)d_in[9];
    float* out = (float*)d_out;

    int N = in_sizes[0] / D;
    int E = in_sizes[1] / 2;
    int NBLK = (N + 63) / 64;                    // 782 gemm blocks
    int Npad = NBLK * 64;

    // workspace layout (~61 MB):
    //   fout [Npad*128 f32] | xb [Npad*64 uint bf16-pairs] | Bsw [32768 bf16]
    //   gsum | gsumsq [G*D f32] | cnt[N] | bnd[G+1] | adj[N*CAP] | Aag [Npad*64 uint]
    float*          fout = (float*)d_ws;
    unsigned int*   xb   = (unsigned int*)(fout + (size_t)Npad * D);
    unsigned short* Bsw  = (unsigned short*)(xb + (size_t)Npad * 64);
    float* gsum   = (float*)(Bsw + 32768);
    float* gsumsq = gsum + NGRAPH * D;
    int*   cnt    = (int*)(gsumsq + NGRAPH * D);
    int*   bnd    = cnt + N;
    int*   adj    = bnd + (NGRAPH + 1);
    unsigned int* Aag = (unsigned int*)(adj + (size_t)N * CAP);

    // zero gsum, gsumsq, cnt (contiguous)
    hipMemsetAsync(gsum, 0, (2 * NGRAPH * D) * sizeof(float) + (size_t)N * sizeof(int), stream);

    int fillB = (E + 255) / 256;
    int xbB   = (Npad * 32 + 255) / 256;
    prep_fill_kernel<<<129 + fillB + xbB, 256, 0, stream>>>(
        Wl, Wr, Bsw, x, xb, batch, bnd, ei, cnt, adj, N, E, Npad, fillB);

    aggregate_kernel<<<Npad / 4, 256, 0, stream>>>(xb, cnt, adj, Aag, N, Npad);

    gemm_kernel<<<NBLK, 256, 0, stream>>>(
        (const unsigned short*)Aag, (const unsigned short*)xb, Bsw, bl, batch,
        fout, gsum, gsumsq, N);

    {
        int threads = N * (D / 4);
        final_kernel<<<(threads + 255) / 256, 256, 0, stream>>>(
            fout, x, batch, bnd, gsum, gsumsq, ms, gw, gb, out, N);
    }
}